// Round 3
// baseline (297.704 us; speedup 1.0000x reference)
//
#include <hip/hip_runtime.h>
#include <math.h>

#define N_NODES 60000
#define N_EDGES 240000
#define F_INQ 10
#define G_DIM 512
#define NB_SCAN ((N_NODES + 255) / 256)   // 235

__device__ __forceinline__ void atomic_add_f32(float* addr, float v) {
    unsafeAtomicAdd(addr, v);
}

// ===========================================================================
// CSR build: deg histogram -> 3-kernel exclusive scan (in-place) -> fill.
// After k_fill, rs[i] = end offset of node i (start = rs[i-1], rs[-1]=0).
// ===========================================================================
__global__ __launch_bounds__(256) void k_deg(
    const int* __restrict__ ei, int* __restrict__ rs)
{
    int e = blockIdx.x * 256 + threadIdx.x;
    if (e < N_EDGES) atomicAdd(&rs[ei[e]], 1);
}

__global__ __launch_bounds__(256) void k_scan_a(
    int* __restrict__ rs, int* __restrict__ bsum)
{
    __shared__ int s[256];
    int i = blockIdx.x * 256 + threadIdx.x;
    int v = (i < N_NODES) ? rs[i] : 0;
    s[threadIdx.x] = v;
    __syncthreads();
    for (int off = 1; off < 256; off <<= 1) {
        int t = (threadIdx.x >= off) ? s[threadIdx.x - off] : 0;
        __syncthreads();
        s[threadIdx.x] += t;
        __syncthreads();
    }
    if (i < N_NODES) rs[i] = s[threadIdx.x] - v;  // exclusive
    if (threadIdx.x == 255) bsum[blockIdx.x] = s[255];
}

__global__ __launch_bounds__(256) void k_scan_b(int* __restrict__ bsum)
{
    __shared__ int s[256];
    int v = (threadIdx.x < NB_SCAN) ? bsum[threadIdx.x] : 0;
    s[threadIdx.x] = v;
    __syncthreads();
    for (int off = 1; off < 256; off <<= 1) {
        int t = (threadIdx.x >= off) ? s[threadIdx.x - off] : 0;
        __syncthreads();
        s[threadIdx.x] += t;
        __syncthreads();
    }
    if (threadIdx.x < NB_SCAN) bsum[threadIdx.x] = s[threadIdx.x] - v;  // exclusive
}

__global__ __launch_bounds__(256) void k_scan_c(
    int* __restrict__ rs, const int* __restrict__ bsum)
{
    int i = blockIdx.x * 256 + threadIdx.x;
    if (i < N_NODES) rs[i] += bsum[blockIdx.x];
}

__global__ __launch_bounds__(256) void k_fill(
    const int* __restrict__ ei, int* __restrict__ rs, int* __restrict__ csr)
{
    int e = blockIdx.x * 256 + threadIdx.x;
    if (e >= N_EDGES) return;
    int slot = atomicAdd(&rs[ei[e]], 1);
    csr[slot] = e;
}

// ---------------------------------------------------------------------------
// K1: per-node transform 1 (grid-stride, weights staged once per block).
// Packs per node (96 floats):
//   [ xW_gcn1(16) | z1_s0(16) | z1_s1(16) | z1_s2(16) | z1_bias(16) | root1+bias1(16) ]
// ---------------------------------------------------------------------------
__global__ __launch_bounds__(256) void k1_node1(
    const float* __restrict__ x,
    const float* __restrict__ Wg1,   // [10,16]
    const float* __restrict__ We1,   // [3,160]
    const float* __restrict__ be1,   // [160]
    const float* __restrict__ root1, // [160]
    const float* __restrict__ bias1, // [16]
    float* __restrict__ A)           // [N,96]
{
    __shared__ float w[6 * 168 + 16];
    for (int t = threadIdx.x; t < 6 * 168 + 16; t += 256) {
        float v = 0.f;
        if (t >= 6 * 168) v = bias1[t - 6 * 168];
        else {
            int slot = t / 168, r = t - slot * 168;
            if (r < 160) {
                if (slot == 0)      v = Wg1[r];
                else if (slot <= 3) v = We1[(slot - 1) * 160 + r];
                else if (slot == 4) v = be1[r];
                else                v = root1[r];
            }
        }
        w[t] = v;
    }
    __syncthreads();
    const int total = N_NODES * 96;
    const int stride = gridDim.x * 256;
    for (int idx = blockIdx.x * 256 + threadIdx.x; idx < total; idx += stride) {
        int node = idx / 96;
        int j = idx - node * 96;
        int slot = j >> 4, o = j & 15;
        const float* xp = x + node * F_INQ;
        const float* wp = w + slot * 168 + o;
        float acc = (slot == 5) ? w[6 * 168 + o] : 0.f;
#pragma unroll
        for (int f = 0; f < F_INQ; ++f)
            acc += xp[f] * wp[f * 16];
        A[idx] = acc;
    }
}

// ---------------------------------------------------------------------------
// K_gather1: layer-1 aggregation as CSR gather (no fp32 atomics) + fused
// bias/root + relu. Thread per (node, o<16).
// ---------------------------------------------------------------------------
__global__ __launch_bounds__(256) void k_gather1(
    const float* __restrict__ A,
    const int* __restrict__ rs,       // end offsets
    const int* __restrict__ csr,
    const int* __restrict__ ei,       // [2,E]
    const float* __restrict__ a_vals,
    const float* __restrict__ efeat,  // [E,3]
    const float* __restrict__ b_gcn1,
    float* __restrict__ g1, float* __restrict__ c1)
{
    int idx = blockIdx.x * 256 + threadIdx.x;
    int node = idx >> 4, o = idx & 15;
    if (node >= N_NODES) return;
    int start = (node > 0) ? rs[node - 1] : 0;
    int end = rs[node];
    float g = 0.f, c = 0.f;
    for (int k = start; k < end; ++k) {
        int e = csr[k];
        int col = ei[N_EDGES + e];
        float a  = a_vals[e];
        float e0 = efeat[e * 3 + 0], e1 = efeat[e * 3 + 1], e2 = efeat[e * 3 + 2];
        const float* Ac = A + col * 96;
        g += a * Ac[o];
        c += Ac[64 + o] + e0 * Ac[16 + o] + e1 * Ac[32 + o] + e2 * Ac[48 + o];
    }
    float gv = g + b_gcn1[o];
    g1[node * 16 + o] = gv > 0.f ? gv : 0.f;
    float cv = c + A[node * 96 + 80 + o];
    c1[node * 16 + o] = cv > 0.f ? cv : 0.f;
}

// ---------------------------------------------------------------------------
// K4b: per-node transform 2 (grid-stride, weights once per block, float4 in).
// Packs per node (192 floats):
//   [ g1@W_gcn2(32) | z2_s0(32) | z2_s1(32) | z2_s2(32) | z2_bias(32) | root2+bias2(32) ]
// ---------------------------------------------------------------------------
__global__ __launch_bounds__(256) void k4b_node2(
    const float* __restrict__ g1,
    const float* __restrict__ c1,
    const float* __restrict__ Wg2,   // [16,32]
    const float* __restrict__ We2,   // [3,512]
    const float* __restrict__ be2,   // [512]
    const float* __restrict__ root2, // [512]
    const float* __restrict__ bias2, // [32]
    float* __restrict__ B)           // [N,192]
{
    __shared__ float w[6 * 520 + 32];
    for (int t = threadIdx.x; t < 6 * 520 + 32; t += 256) {
        float v = 0.f;
        if (t >= 6 * 520) v = bias2[t - 6 * 520];
        else {
            int slot = t / 520, r = t - slot * 520;
            if (r < 512) {
                if (slot == 0)      v = Wg2[r];
                else if (slot <= 3) v = We2[(slot - 1) * 512 + r];
                else if (slot == 4) v = be2[r];
                else                v = root2[r];
            }
        }
        w[t] = v;
    }
    __syncthreads();
    const int total = N_NODES * 192;
    const int stride = gridDim.x * 256;
    for (int idx = blockIdx.x * 256 + threadIdx.x; idx < total; idx += stride) {
        int node = idx / 192;
        int j = idx - node * 192;
        int slot = j >> 5, o = j & 31;
        const float* in = (slot == 0 ? g1 : c1) + node * 16;
        const float4* inv = reinterpret_cast<const float4*>(in);
        float4 i0 = inv[0], i1 = inv[1], i2 = inv[2], i3 = inv[3];
        const float* wp = w + slot * 520 + o;
        float acc = (slot == 5) ? w[6 * 520 + o] : 0.f;
        acc += i0.x * wp[0 * 32] + i0.y * wp[1 * 32] + i0.z * wp[2 * 32] + i0.w * wp[3 * 32];
        acc += i1.x * wp[4 * 32] + i1.y * wp[5 * 32] + i1.z * wp[6 * 32] + i1.w * wp[7 * 32];
        acc += i2.x * wp[8 * 32] + i2.y * wp[9 * 32] + i2.z * wp[10 * 32] + i2.w * wp[11 * 32];
        acc += i3.x * wp[12 * 32] + i3.y * wp[13 * 32] + i3.z * wp[14 * 32] + i3.w * wp[15 * 32];
        B[idx] = acc;
    }
}

// ---------------------------------------------------------------------------
// K_gather2: layer-2 aggregation as CSR gather + fused bias/root + relu.
// Thread per (node, o<32). Writes final g2/c2 (post-relu).
// ---------------------------------------------------------------------------
__global__ __launch_bounds__(256) void k_gather2(
    const float* __restrict__ B,
    const int* __restrict__ rs,
    const int* __restrict__ csr,
    const int* __restrict__ ei,
    const float* __restrict__ a_vals,
    const float* __restrict__ efeat,
    const float* __restrict__ b_gcn2,
    float* __restrict__ g2, float* __restrict__ c2)
{
    int idx = blockIdx.x * 256 + threadIdx.x;
    int node = idx >> 5, o = idx & 31;
    if (node >= N_NODES) return;
    int start = (node > 0) ? rs[node - 1] : 0;
    int end = rs[node];
    float g = 0.f, c = 0.f;
    for (int k = start; k < end; ++k) {
        int e = csr[k];
        int col = ei[N_EDGES + e];
        float a  = a_vals[e];
        float e0 = efeat[e * 3 + 0], e1 = efeat[e * 3 + 1], e2 = efeat[e * 3 + 2];
        const float* Bc = B + col * 192;
        g += a * Bc[o];
        c += Bc[128 + o] + e0 * Bc[32 + o] + e1 * Bc[64 + o] + e2 * Bc[96 + o];
    }
    float gv = g + b_gcn2[o];
    g2[node * 32 + o] = gv > 0.f ? gv : 0.f;
    float cv = c + B[node * 192 + 160 + o];
    c2[node * 32 + o] = cv > 0.f ? cv : 0.f;
}

// ---------------------------------------------------------------------------
// K7: global sum pool exploiting sorted seg. Each wave walks 64 consecutive
// nodes (lane = channel j<64), register-accumulates, flushes to p only on
// graph-boundary change (wave-uniform branch). ~90K atomics vs 3.84M.
// ---------------------------------------------------------------------------
__global__ __launch_bounds__(256) void k7_pool(
    const float* __restrict__ g2, const float* __restrict__ c2,
    const int* __restrict__ seg,
    float* __restrict__ p)
{
    int t = threadIdx.x;
    int wave = t >> 6;
    int j = t & 63;
    int base = blockIdx.x * 256 + wave * 64;
    float acc = 0.f;
    int cur = -1;
    for (int n = 0; n < 64; ++n) {
        int node = base + n;
        if (node >= N_NODES) break;
        int s = seg[node];
        if (s != cur) {
            if (cur >= 0) atomic_add_f32(&p[cur * 64 + j], acc);
            cur = s;
            acc = 0.f;
        }
        float v = (j < 32) ? g2[node * 32 + j] : c2[node * 32 + (j - 32)];
        acc += v;
    }
    if (cur >= 0) atomic_add_f32(&p[cur * 64 + j], acc);
}

// ---------------------------------------------------------------------------
// K8: MLP head, one thread per graph. 64 -> 16 -> 8 -> sigmoid(1).
// ---------------------------------------------------------------------------
__global__ __launch_bounds__(256) void k8_head(
    const float* __restrict__ p,
    const float* __restrict__ Wd1, const float* __restrict__ bd1,
    const float* __restrict__ Wd2, const float* __restrict__ bd2,
    const float* __restrict__ Wo,  const float* __restrict__ bo,
    float* __restrict__ out)
{
    __shared__ float w1[64 * 16], b1[16], w2[16 * 8], b2[8], wo[8], bos;
    for (int t = threadIdx.x; t < 1024; t += 256) w1[t] = Wd1[t];
    if (threadIdx.x < 128) w2[threadIdx.x] = Wd2[threadIdx.x];
    if (threadIdx.x < 16)  b1[threadIdx.x] = bd1[threadIdx.x];
    if (threadIdx.x < 8) { b2[threadIdx.x] = bd2[threadIdx.x]; wo[threadIdx.x] = Wo[threadIdx.x]; }
    if (threadIdx.x == 0)  bos = bo[0];
    __syncthreads();
    int g = blockIdx.x * 256 + threadIdx.x;
    if (g >= G_DIM) return;
    float pl[64];
#pragma unroll
    for (int k = 0; k < 64; ++k) pl[k] = p[g * 64 + k];
    float h1[16];
#pragma unroll
    for (int i = 0; i < 16; ++i) {
        float acc = b1[i];
#pragma unroll
        for (int k = 0; k < 64; ++k) acc += pl[k] * w1[k * 16 + i];
        h1[i] = acc > 0.f ? acc : 0.f;
    }
    float h2[8];
#pragma unroll
    for (int i = 0; i < 8; ++i) {
        float acc = b2[i];
#pragma unroll
        for (int k = 0; k < 16; ++k) acc += h1[k] * w2[k * 8 + i];
        h2[i] = acc > 0.f ? acc : 0.f;
    }
    float t = bos;
#pragma unroll
    for (int k = 0; k < 8; ++k) t += h2[k] * wo[k];
    out[g] = 1.f / (1.f + expf(-t));
}

// ---------------------------------------------------------------------------
// Workspace layout:
//   floats: [0, N*192) A/B overlay | g1 N*16 | c1 N*16 | g2 N*32 | c2 N*32 | p G*64
//   ints  : rs[N] | csr[E] | bsum[256]
// Total ~70.5 MB.
// ---------------------------------------------------------------------------
extern "C" void kernel_launch(void* const* d_in, const int* in_sizes, int n_in,
                              void* d_out, int out_size, void* d_ws, size_t ws_size,
                              hipStream_t stream)
{
    const float* x      = (const float*)d_in[0];
    const float* a_vals = (const float*)d_in[1];
    const float* efeat  = (const float*)d_in[2];
    const int*   ei     = (const int*)d_in[3];
    const int*   seg    = (const int*)d_in[4];
    const float* Wg1    = (const float*)d_in[5];
    const float* bg1    = (const float*)d_in[6];
    const float* Wg2    = (const float*)d_in[7];
    const float* bg2    = (const float*)d_in[8];
    const float* We1    = (const float*)d_in[9];
    const float* be1    = (const float*)d_in[10];
    const float* root1  = (const float*)d_in[11];
    const float* bias1  = (const float*)d_in[12];
    const float* We2    = (const float*)d_in[13];
    const float* be2    = (const float*)d_in[14];
    const float* root2  = (const float*)d_in[15];
    const float* bias2  = (const float*)d_in[16];
    const float* Wd1    = (const float*)d_in[17];
    const float* bd1    = (const float*)d_in[18];
    const float* Wd2    = (const float*)d_in[19];
    const float* bd2    = (const float*)d_in[20];
    const float* Wo     = (const float*)d_in[21];
    const float* bo     = (const float*)d_in[22];

    float* ws  = (float*)d_ws;
    float* A   = ws;
    float* B   = ws;
    float* g1  = ws + (size_t)N_NODES * 192;
    float* c1  = g1 + (size_t)N_NODES * 16;
    float* g2  = c1 + (size_t)N_NODES * 16;
    float* c2  = g2 + (size_t)N_NODES * 32;
    float* p   = c2 + (size_t)N_NODES * 32;
    int*   rs   = (int*)(p + (size_t)G_DIM * 64);
    int*   csr  = rs + N_NODES;
    int*   bsum = csr + N_EDGES;
    float* out  = (float*)d_out;

    hipMemsetAsync(rs, 0, sizeof(int) * N_NODES, stream);
    hipMemsetAsync(p,  0, sizeof(float) * G_DIM * 64, stream);

    // CSR build (int atomics only)
    k_deg   <<<(N_EDGES + 255) / 256, 256, 0, stream>>>(ei, rs);
    k_scan_a<<<NB_SCAN, 256, 0, stream>>>(rs, bsum);
    k_scan_b<<<1, 256, 0, stream>>>(bsum);
    k_scan_c<<<NB_SCAN, 256, 0, stream>>>(rs, bsum);
    k_fill  <<<(N_EDGES + 255) / 256, 256, 0, stream>>>(ei, rs, csr);

    // Model pipeline (gather form, no fp32 scatter atomics)
    k1_node1 <<<1280, 256, 0, stream>>>(x, Wg1, We1, be1, root1, bias1, A);
    k_gather1<<<N_NODES * 16 / 256, 256, 0, stream>>>(A, rs, csr, ei, a_vals, efeat, bg1, g1, c1);
    k4b_node2<<<1280, 256, 0, stream>>>(g1, c1, Wg2, We2, be2, root2, bias2, B);
    k_gather2<<<N_NODES * 32 / 256, 256, 0, stream>>>(B, rs, csr, ei, a_vals, efeat, bg2, g2, c2);
    k7_pool  <<<NB_SCAN, 256, 0, stream>>>(g2, c2, seg, p);
    k8_head  <<<2, 256, 0, stream>>>(p, Wd1, bd1, Wd2, bd2, Wo, bo, out);
}